// Round 1
// baseline (1667.271 us; speedup 1.0000x reference)
//
#include <hip/hip_runtime.h>
#include <hip/hip_bf16.h>
#include <math.h>

// Problem constants (from reference): B=4, T=2048, D=1024, E=8, F=1024, top_k=2
#define NTOK 8192   // B*T
#define D_DIM 1024
#define E_DIM 8
#define F_DIM 1024

#define TM 64
#define TN 64
#define BK 16

// ---------------- Kernel 1: router + expert assignment ----------------
// One block (256 threads) per token. Computes logits, softmax, top-2,
// second softmax over the two probabilities, appends (token*2+slot, weight)
// to per-expert lists via atomics.
__global__ __launch_bounds__(256) void router_kernel(
    const float* __restrict__ x,      // [NTOK][D]
    const float* __restrict__ Wr,     // [D][E]
    int* __restrict__ cnt,            // [E]
    int* __restrict__ tok_of,         // [E][NTOK]
    float* __restrict__ wt_of)        // [E][NTOK]
{
    const int t = blockIdx.x;
    const int tid = threadIdx.x;
    __shared__ float xs[D_DIM];
    __shared__ float red[E_DIM][256];

    // load x row (256 threads x float4 = 1024 floats)
    {
        float4 v = *(const float4*)(x + (size_t)t * D_DIM + tid * 4);
        *(float4*)&xs[tid * 4] = v;
    }
    __syncthreads();

    float p[E_DIM];
    #pragma unroll
    for (int e = 0; e < E_DIM; ++e) p[e] = 0.f;
    for (int d = tid; d < D_DIM; d += 256) {
        float xd = xs[d];
        #pragma unroll
        for (int e = 0; e < E_DIM; ++e) p[e] += xd * Wr[d * E_DIM + e];
    }
    #pragma unroll
    for (int e = 0; e < E_DIM; ++e) red[e][tid] = p[e];
    __syncthreads();
    for (int s = 128; s > 0; s >>= 1) {
        if (tid < s) {
            #pragma unroll
            for (int e = 0; e < E_DIM; ++e) red[e][tid] += red[e][tid + s];
        }
        __syncthreads();
    }
    if (tid == 0) {
        float logits[E_DIM];
        #pragma unroll
        for (int e = 0; e < E_DIM; ++e) logits[e] = red[e][0];
        // softmax over 8
        float m = logits[0];
        #pragma unroll
        for (int e = 1; e < E_DIM; ++e) m = fmaxf(m, logits[e]);
        float pr[E_DIM], sum = 0.f;
        #pragma unroll
        for (int e = 0; e < E_DIM; ++e) { pr[e] = expf(logits[e] - m); sum += pr[e]; }
        float inv = 1.f / sum;
        #pragma unroll
        for (int e = 0; e < E_DIM; ++e) pr[e] *= inv;
        // top-2 (strict > keeps lowest index on ties, matching lax.top_k)
        int e0 = 0;
        #pragma unroll
        for (int e = 1; e < E_DIM; ++e) if (pr[e] > pr[e0]) e0 = e;
        int e1 = (e0 == 0) ? 1 : 0;
        #pragma unroll
        for (int e = 0; e < E_DIM; ++e) { if (e != e0 && pr[e] > pr[e1]) e1 = e; }
        // second softmax over the two PROBABILITIES (faithful to reference)
        float b = expf(pr[e1] - pr[e0]);            // <= 1
        float w0 = 1.f / (1.f + b);
        float w1 = b / (1.f + b);
        int pos0 = atomicAdd(&cnt[e0], 1);
        tok_of[e0 * NTOK + pos0] = t * 2 + 0; wt_of[e0 * NTOK + pos0] = w0;
        int pos1 = atomicAdd(&cnt[e1], 1);
        tok_of[e1 * NTOK + pos1] = t * 2 + 1; wt_of[e1 * NTOK + pos1] = w1;
    }
}

// ---------------- Kernel 2: fused gating+up GEMM + silu*mul ----------------
// grid: x = rowTile*CT + colTile (worst case 128*16), y = expert
__global__ __launch_bounds__(256) void gateup_gemm(
    const float* __restrict__ x,      // [NTOK][D]
    const float* __restrict__ Wg,     // [E][D][F]
    const float* __restrict__ Wu,     // [E][D][F]
    const int* __restrict__ cnt,
    const int* __restrict__ tok_of,
    float* __restrict__ H)            // [2*NTOK][F]
{
    const int e = blockIdx.y;
    const int CT = F_DIM / TN;         // 16
    const int rowTile = blockIdx.x / CT;
    const int colTile = blockIdx.x % CT;
    const int rows = cnt[e];
    const int rowBase = rowTile * TM;
    if (rowBase >= rows) return;
    const int colBase = colTile * TN;

    __shared__ float As[BK][TM];
    __shared__ float Bgs[BK][TN];
    __shared__ float Bus[BK][TN];
    __shared__ int   toks[TM];

    const int tid = threadIdx.x;
    if (tid < TM) {
        int idx = rowBase + tid;
        toks[tid] = (idx < rows) ? tok_of[e * NTOK + idx] : tok_of[e * NTOK + rowBase];
    }
    __syncthreads();

    const int tx = tid & 15;
    const int ty = tid >> 4;
    float accg[4][4] = {{0.f}}, accu[4][4] = {{0.f}};

    const float* wgB = Wg + (size_t)e * D_DIM * F_DIM + colBase;
    const float* wuB = Wu + (size_t)e * D_DIM * F_DIM + colBase;

    const int lr = tid >> 2;           // 0..63 X row
    const int lk = (tid & 3) * 4;      // k quad
    const int wk = tid >> 4;           // 0..15 W k-row
    const int wc = (tid & 15) * 4;     // W col quad
    const int trow = toks[lr] >> 1;
    const float* xrow = x + (size_t)trow * D_DIM;

    for (int k0 = 0; k0 < D_DIM; k0 += BK) {
        {
            float4 v = *(const float4*)(xrow + k0 + lk);
            As[lk + 0][lr] = v.x; As[lk + 1][lr] = v.y;
            As[lk + 2][lr] = v.z; As[lk + 3][lr] = v.w;
        }
        {
            float4 g = *(const float4*)(wgB + (size_t)(k0 + wk) * F_DIM + wc);
            *(float4*)&Bgs[wk][wc] = g;
            float4 u = *(const float4*)(wuB + (size_t)(k0 + wk) * F_DIM + wc);
            *(float4*)&Bus[wk][wc] = u;
        }
        __syncthreads();
        #pragma unroll
        for (int k = 0; k < BK; ++k) {
            float a[4], bg[4], bu[4];
            #pragma unroll
            for (int i = 0; i < 4; ++i) a[i] = As[k][ty * 4 + i];
            *(float4*)bg = *(const float4*)&Bgs[k][tx * 4];
            *(float4*)bu = *(const float4*)&Bus[k][tx * 4];
            #pragma unroll
            for (int i = 0; i < 4; ++i)
                #pragma unroll
                for (int j = 0; j < 4; ++j) {
                    accg[i][j] += a[i] * bg[j];
                    accu[i][j] += a[i] * bu[j];
                }
        }
        __syncthreads();
    }

    #pragma unroll
    for (int i = 0; i < 4; ++i) {
        int ridx = rowBase + ty * 4 + i;
        if (ridx < rows) {
            int tok2 = toks[ty * 4 + i];
            float* hrow = H + (size_t)tok2 * F_DIM + colBase;
            float4 o;
            float g, u;
            g = accg[i][0]; u = accu[i][0]; o.x = (g / (1.f + expf(-g))) * u;
            g = accg[i][1]; u = accu[i][1]; o.y = (g / (1.f + expf(-g))) * u;
            g = accg[i][2]; u = accu[i][2]; o.z = (g / (1.f + expf(-g))) * u;
            g = accg[i][3]; u = accu[i][3]; o.w = (g / (1.f + expf(-g))) * u;
            *(float4*)&hrow[tx * 4] = o;
        }
    }
}

// ---------------- Kernel 3: down GEMM + weighted scatter ----------------
__global__ __launch_bounds__(256) void down_gemm(
    const float* __restrict__ H,      // [2*NTOK][F]
    const float* __restrict__ Wd,     // [E][F][D]
    const int* __restrict__ cnt,
    const int* __restrict__ tok_of,
    const float* __restrict__ wt_of,
    float* __restrict__ out)          // [NTOK][D] (pre-zeroed)
{
    const int e = blockIdx.y;
    const int CT = D_DIM / TN;         // 16
    const int rowTile = blockIdx.x / CT;
    const int colTile = blockIdx.x % CT;
    const int rows = cnt[e];
    const int rowBase = rowTile * TM;
    if (rowBase >= rows) return;
    const int colBase = colTile * TN;

    __shared__ float As[BK][TM];
    __shared__ float Bs[BK][TN];
    __shared__ int   toks[TM];
    __shared__ float wts[TM];

    const int tid = threadIdx.x;
    if (tid < TM) {
        int idx = rowBase + tid;
        int safe = (idx < rows) ? idx : rowBase;
        toks[tid] = tok_of[e * NTOK + safe];
        wts[tid]  = wt_of[e * NTOK + safe];
    }
    __syncthreads();

    const int tx = tid & 15;
    const int ty = tid >> 4;
    float acc[4][4] = {{0.f}};

    const float* wdB = Wd + (size_t)e * F_DIM * D_DIM + colBase;

    const int lr = tid >> 2;
    const int lk = (tid & 3) * 4;
    const int wk = tid >> 4;
    const int wc = (tid & 15) * 4;
    const float* hrow = H + (size_t)toks[lr] * F_DIM;

    for (int k0 = 0; k0 < F_DIM; k0 += BK) {
        {
            float4 v = *(const float4*)(hrow + k0 + lk);
            As[lk + 0][lr] = v.x; As[lk + 1][lr] = v.y;
            As[lk + 2][lr] = v.z; As[lk + 3][lr] = v.w;
        }
        {
            float4 w = *(const float4*)(wdB + (size_t)(k0 + wk) * D_DIM + wc);
            *(float4*)&Bs[wk][wc] = w;
        }
        __syncthreads();
        #pragma unroll
        for (int k = 0; k < BK; ++k) {
            float a[4], b[4];
            #pragma unroll
            for (int i = 0; i < 4; ++i) a[i] = As[k][ty * 4 + i];
            *(float4*)b = *(const float4*)&Bs[k][tx * 4];
            #pragma unroll
            for (int i = 0; i < 4; ++i)
                #pragma unroll
                for (int j = 0; j < 4; ++j)
                    acc[i][j] += a[i] * b[j];
        }
        __syncthreads();
    }

    #pragma unroll
    for (int i = 0; i < 4; ++i) {
        int ridx = rowBase + ty * 4 + i;
        if (ridx < rows) {
            int r = ty * 4 + i;
            int t = toks[r] >> 1;
            float w = wts[r];
            float* orow = out + (size_t)t * D_DIM + colBase;
            #pragma unroll
            for (int j = 0; j < 4; ++j)
                atomicAdd(&orow[tx * 4 + j], w * acc[i][j]);
        }
    }
}

extern "C" void kernel_launch(void* const* d_in, const int* in_sizes, int n_in,
                              void* d_out, int out_size, void* d_ws, size_t ws_size,
                              hipStream_t stream) {
    const float* x  = (const float*)d_in[0];   // [B,T,D] f32
    const float* Wr = (const float*)d_in[1];   // [D,E]
    const float* Wg = (const float*)d_in[2];   // [E,D,F]
    const float* Wu = (const float*)d_in[3];   // [E,D,F]
    const float* Wd = (const float*)d_in[4];   // [E,F,D]
    // d_in[5] = top_k (=2), hardcoded
    float* out = (float*)d_out;

    // workspace layout
    char* ws = (char*)d_ws;
    int*   cnt    = (int*)ws;                              // 8 ints (pad to 256B)
    int*   tok_of = (int*)(ws + 256);                      // E*NTOK ints   (256 KB)
    float* wt_of  = (float*)(ws + 256 + E_DIM * NTOK * 4); // E*NTOK floats (256 KB)
    float* H      = (float*)(ws + 256 + 2 * E_DIM * NTOK * 4); // [2*NTOK][F] f32 (64 MB)

    hipMemsetAsync(cnt, 0, E_DIM * sizeof(int), stream);
    hipMemsetAsync(d_out, 0, (size_t)out_size * sizeof(float), stream);

    router_kernel<<<NTOK, 256, 0, stream>>>(x, Wr, cnt, tok_of, wt_of);

    dim3 g2((NTOK / TM) * (F_DIM / TN), E_DIM);   // worst-case rows per expert
    gateup_gemm<<<g2, 256, 0, stream>>>(x, Wg, Wu, cnt, tok_of, H);

    dim3 g3((NTOK / TM) * (D_DIM / TN), E_DIM);
    down_gemm<<<g3, 256, 0, stream>>>(H, Wd, cnt, tok_of, wt_of, out);
}

// Round 2
// 541.759 us; speedup vs baseline: 3.0775x; 3.0775x over previous
//
#include <hip/hip_runtime.h>
#include <hip/hip_bf16.h>
#include <math.h>

// B=4, T=2048, D=1024, E=8, F=1024, top_k=2
#define NTOK 8192   // B*T
#define D_DIM 1024
#define E_DIM 8
#define F_DIM 1024

typedef __attribute__((ext_vector_type(8))) short bf16x8;
typedef __attribute__((ext_vector_type(4))) float f32x4;

typedef const __attribute__((address_space(1))) unsigned int* as1_uint_ptr;
typedef __attribute__((address_space(3))) unsigned int* as3_uint_ptr;

__device__ __forceinline__ void async_load16(const void* g, void* l) {
    // per-lane global address; LDS dest = wave-uniform base + lane*16
    __builtin_amdgcn_global_load_lds((as1_uint_ptr)g, (as3_uint_ptr)l, 16, 0, 0);
}

__device__ __forceinline__ float bf2f(unsigned short b) {
    unsigned int u = ((unsigned int)b) << 16;
    return __builtin_bit_cast(float, u);
}
__device__ __forceinline__ unsigned short f2bf(float f) {
    __hip_bfloat16 h = __float2bfloat16(f);
    return __builtin_bit_cast(unsigned short, h);
}

// ---------------- Kernel 1: router + expert assignment ----------------
__global__ __launch_bounds__(256) void router_kernel(
    const float* __restrict__ x,      // [NTOK][D]
    const float* __restrict__ Wr,     // [D][E]
    int* __restrict__ cnt,            // [E]
    int* __restrict__ tok_of,         // [E][NTOK] (tok2 = t*2+slot)
    float* __restrict__ wt2)          // [2*NTOK] weight by tok2
{
    const int t = blockIdx.x;
    const int tid = threadIdx.x;
    __shared__ float xs[D_DIM];
    __shared__ float red[E_DIM][256];

    {
        float4 v = *(const float4*)(x + (size_t)t * D_DIM + tid * 4);
        *(float4*)&xs[tid * 4] = v;
    }
    __syncthreads();

    float p[E_DIM];
    #pragma unroll
    for (int e = 0; e < E_DIM; ++e) p[e] = 0.f;
    for (int d = tid; d < D_DIM; d += 256) {
        float xd = xs[d];
        #pragma unroll
        for (int e = 0; e < E_DIM; ++e) p[e] += xd * Wr[d * E_DIM + e];
    }
    #pragma unroll
    for (int e = 0; e < E_DIM; ++e) red[e][tid] = p[e];
    __syncthreads();
    for (int s = 128; s > 0; s >>= 1) {
        if (tid < s) {
            #pragma unroll
            for (int e = 0; e < E_DIM; ++e) red[e][tid] += red[e][tid + s];
        }
        __syncthreads();
    }
    if (tid == 0) {
        float logits[E_DIM];
        #pragma unroll
        for (int e = 0; e < E_DIM; ++e) logits[e] = red[e][0];
        float m = logits[0];
        #pragma unroll
        for (int e = 1; e < E_DIM; ++e) m = fmaxf(m, logits[e]);
        float pr[E_DIM], sum = 0.f;
        #pragma unroll
        for (int e = 0; e < E_DIM; ++e) { pr[e] = expf(logits[e] - m); sum += pr[e]; }
        float inv = 1.f / sum;
        #pragma unroll
        for (int e = 0; e < E_DIM; ++e) pr[e] *= inv;
        int e0 = 0;
        #pragma unroll
        for (int e = 1; e < E_DIM; ++e) if (pr[e] > pr[e0]) e0 = e;
        int e1 = (e0 == 0) ? 1 : 0;
        #pragma unroll
        for (int e = 0; e < E_DIM; ++e) { if (e != e0 && pr[e] > pr[e1]) e1 = e; }
        // second softmax over the two PROBABILITIES (faithful to reference)
        float b = expf(pr[e1] - pr[e0]);
        float w0 = 1.f / (1.f + b);
        float w1 = b / (1.f + b);
        int pos0 = atomicAdd(&cnt[e0], 1);
        tok_of[e0 * NTOK + pos0] = t * 2 + 0;
        int pos1 = atomicAdd(&cnt[e1], 1);
        tok_of[e1 * NTOK + pos1] = t * 2 + 1;
        wt2[t * 2 + 0] = w0;
        wt2[t * 2 + 1] = w1;
    }
}

// ---------------- Kernel 2: cast x fp32 -> bf16 ----------------
__global__ __launch_bounds__(256) void cast_x_kernel(
    const float* __restrict__ x, unsigned short* __restrict__ xb)
{
    size_t i = ((size_t)blockIdx.x * 256 + threadIdx.x) * 4;
    float4 v = *(const float4*)(x + i);
    ushort4 o;
    o.x = f2bf(v.x); o.y = f2bf(v.y); o.z = f2bf(v.z); o.w = f2bf(v.w);
    *(ushort4*)(xb + i) = o;
}

// ---------------- Kernel 3: cast+transpose weights -> [E][N][K] bf16 ------
// handles 24 matrices of 1024x1024: z<8 -> Wg, z<16 -> Wu, else Wd
__global__ __launch_bounds__(256) void transpose_cast_kernel(
    const float* __restrict__ Wg, const float* __restrict__ Wu,
    const float* __restrict__ Wd,
    unsigned short* __restrict__ WgT, unsigned short* __restrict__ WuT,
    unsigned short* __restrict__ WdT)
{
    const int m = blockIdx.z;
    const float* src;
    unsigned short* dst;
    if (m < 8)       { src = Wg + (size_t)m * 1048576;        dst = WgT + (size_t)m * 1048576; }
    else if (m < 16) { src = Wu + (size_t)(m - 8) * 1048576;  dst = WuT + (size_t)(m - 8) * 1048576; }
    else             { src = Wd + (size_t)(m - 16) * 1048576; dst = WdT + (size_t)(m - 16) * 1048576; }

    const int c0 = blockIdx.x * 64;   // src col tile (= dst row)
    const int r0 = blockIdx.y * 64;   // src row tile (= dst col)
    __shared__ float tile[64][65];
    const int tid = threadIdx.x;
    const int tr = tid >> 4;          // 0..15
    const int tc = (tid & 15) * 4;
    #pragma unroll
    for (int p = 0; p < 4; ++p) {
        float4 v = *(const float4*)(src + (size_t)(r0 + p * 16 + tr) * 1024 + c0 + tc);
        tile[p * 16 + tr][tc + 0] = v.x;
        tile[p * 16 + tr][tc + 1] = v.y;
        tile[p * 16 + tr][tc + 2] = v.z;
        tile[p * 16 + tr][tc + 3] = v.w;
    }
    __syncthreads();
    const int orow = tid >> 3;        // 0..31
    const int ocol = (tid & 7) * 8;
    #pragma unroll
    for (int p = 0; p < 2; ++p) {
        int fr = p * 32 + orow;       // dst row within tile (= src col)
        union { unsigned short s[8]; uint4 v; } pk;
        #pragma unroll
        for (int q = 0; q < 8; ++q) pk.s[q] = f2bf(tile[ocol + q][fr]);
        *(uint4*)&dst[(size_t)(c0 + fr) * 1024 + r0 + ocol] = pk.v;
    }
}

// ---------------- Kernel 4: fused gating+up MFMA GEMM + silu*mul ----------
// C = gather(x) * Wg^T / Wu^T per expert; 128x128 tile, BK=32, 4 waves.
__global__ __launch_bounds__(256, 2) void gateup_mfma(
    const unsigned short* __restrict__ xb,    // [NTOK][D] bf16
    const unsigned short* __restrict__ WgT,   // [E][F][D] bf16 (B^T)
    const unsigned short* __restrict__ WuT,   // [E][F][D] bf16
    const int* __restrict__ cnt,
    const int* __restrict__ tok_of,
    unsigned short* __restrict__ H)           // [2*NTOK][F] bf16
{
    const int e = blockIdx.y;
    const int rowTile = blockIdx.x >> 3;
    const int colTile = blockIdx.x & 7;
    const int rows = cnt[e];
    const int rowBase = rowTile * 128;
    if (rowBase >= rows) return;
    const int n0 = colTile * 128;

    __shared__ short As[128 * 32];
    __shared__ short Bg[128 * 32];
    __shared__ short Bu[128 * 32];
    __shared__ int toks[128];

    const int tid = threadIdx.x;
    if (tid < 128) {
        int idx = rowBase + tid;
        toks[tid] = tok_of[e * NTOK + (idx < rows ? idx : rows - 1)];
    }
    __syncthreads();

    const int lane = tid & 63;
    const int w = tid >> 6;
    const int seg0 = w * 2, seg1 = w * 2 + 1;   // each wave stages 2 segs per buffer
    const int sr = lane >> 2;                   // 0..15 row within segment
    const int sk = (lane & 3) * 8;              // k element offset (8 bf16 = 16B)

    const int ar0 = seg0 * 16 + sr;
    const int ar1 = seg1 * 16 + sr;
    const unsigned short* aG0 = xb + (size_t)(toks[ar0] >> 1) * D_DIM + sk;
    const unsigned short* aG1 = xb + (size_t)(toks[ar1] >> 1) * D_DIM + sk;
    const unsigned short* WgTe = WgT + (size_t)e * F_DIM * D_DIM;
    const unsigned short* WuTe = WuT + (size_t)e * F_DIM * D_DIM;
    const unsigned short* gG0 = WgTe + (size_t)(n0 + ar0) * D_DIM + sk;
    const unsigned short* gG1 = WgTe + (size_t)(n0 + ar1) * D_DIM + sk;
    const unsigned short* uG0 = WuTe + (size_t)(n0 + ar0) * D_DIM + sk;
    const unsigned short* uG1 = WuTe + (size_t)(n0 + ar1) * D_DIM + sk;

    short* aL0 = &As[seg0 * 512];   // 1 KB per segment
    short* aL1 = &As[seg1 * 512];
    short* gL0 = &Bg[seg0 * 512];
    short* gL1 = &Bg[seg1 * 512];
    short* uL0 = &Bu[seg0 * 512];
    short* uL1 = &Bu[seg1 * 512];

    const int mbase = (w >> 1) * 64;
    const int nbase = (w & 1) * 64;
    const int fr = lane & 15;
    const int fk = (lane >> 4) * 8;

    f32x4 accg[4][4], accu[4][4];
    #pragma unroll
    for (int i = 0; i < 4; ++i)
        #pragma unroll
        for (int j = 0; j < 4; ++j) { accg[i][j] = (f32x4)(0.f); accu[i][j] = (f32x4)(0.f); }

    for (int k0 = 0; k0 < D_DIM; k0 += 32) {
        async_load16(aG0 + k0, aL0);
        async_load16(aG1 + k0, aL1);
        async_load16(gG0 + k0, gL0);
        async_load16(gG1 + k0, gL1);
        async_load16(uG0 + k0, uL0);
        async_load16(uG1 + k0, uL1);
        __syncthreads();

        bf16x8 a[4], g[4], u[4];
        #pragma unroll
        for (int i = 0; i < 4; ++i)
            a[i] = *(const bf16x8*)&As[(mbase + i * 16 + fr) * 32 + fk];
        #pragma unroll
        for (int j = 0; j < 4; ++j) {
            g[j] = *(const bf16x8*)&Bg[(nbase + j * 16 + fr) * 32 + fk];
            u[j] = *(const bf16x8*)&Bu[(nbase + j * 16 + fr) * 32 + fk];
        }
        #pragma unroll
        for (int i = 0; i < 4; ++i)
            #pragma unroll
            for (int j = 0; j < 4; ++j) {
                accg[i][j] = __builtin_amdgcn_mfma_f32_16x16x32_bf16(a[i], g[j], accg[i][j], 0, 0, 0);
                accu[i][j] = __builtin_amdgcn_mfma_f32_16x16x32_bf16(a[i], u[j], accu[i][j], 0, 0, 0);
            }
        __syncthreads();
    }

    // epilogue: C/D layout col=lane&15, row=(lane>>4)*4+reg
    const int erow = (lane >> 4) * 4;
    #pragma unroll
    for (int i = 0; i < 4; ++i) {
        #pragma unroll
        for (int r = 0; r < 4; ++r) {
            int row = mbase + i * 16 + erow + r;
            int idx = rowBase + row;
            if (idx < rows) {
                int tok2 = toks[row];
                unsigned short* hrow = H + (size_t)tok2 * F_DIM + n0 + nbase;
                #pragma unroll
                for (int j = 0; j < 4; ++j) {
                    float gg = accg[i][j][r];
                    float uu = accu[i][j][r];
                    float h = gg / (1.f + __expf(-gg)) * uu;
                    hrow[j * 16 + fr] = f2bf(h);
                }
            }
        }
    }
}

// ---------------- Kernel 5: down MFMA GEMM -> Hd (unweighted) -------------
__global__ __launch_bounds__(256, 2) void down_mfma(
    const unsigned short* __restrict__ H,     // [2*NTOK][F] bf16
    const unsigned short* __restrict__ WdT,   // [E][D][F] bf16 (B^T)
    const int* __restrict__ cnt,
    const int* __restrict__ tok_of,
    unsigned short* __restrict__ Hd)          // [2*NTOK][D] bf16
{
    const int e = blockIdx.y;
    const int rowTile = blockIdx.x >> 3;
    const int colTile = blockIdx.x & 7;
    const int rows = cnt[e];
    const int rowBase = rowTile * 128;
    if (rowBase >= rows) return;
    const int n0 = colTile * 128;

    __shared__ short As[128 * 32];
    __shared__ short Bs[128 * 32];
    __shared__ int toks[128];

    const int tid = threadIdx.x;
    if (tid < 128) {
        int idx = rowBase + tid;
        toks[tid] = tok_of[e * NTOK + (idx < rows ? idx : rows - 1)];
    }
    __syncthreads();

    const int lane = tid & 63;
    const int w = tid >> 6;
    const int seg0 = w * 2, seg1 = w * 2 + 1;
    const int sr = lane >> 2;
    const int sk = (lane & 3) * 8;

    const int ar0 = seg0 * 16 + sr;
    const int ar1 = seg1 * 16 + sr;
    const unsigned short* aG0 = H + (size_t)toks[ar0] * F_DIM + sk;
    const unsigned short* aG1 = H + (size_t)toks[ar1] * F_DIM + sk;
    const unsigned short* WdTe = WdT + (size_t)e * D_DIM * F_DIM;
    const unsigned short* bG0 = WdTe + (size_t)(n0 + ar0) * F_DIM + sk;
    const unsigned short* bG1 = WdTe + (size_t)(n0 + ar1) * F_DIM + sk;

    short* aL0 = &As[seg0 * 512];
    short* aL1 = &As[seg1 * 512];
    short* bL0 = &Bs[seg0 * 512];
    short* bL1 = &Bs[seg1 * 512];

    const int mbase = (w >> 1) * 64;
    const int nbase = (w & 1) * 64;
    const int fr = lane & 15;
    const int fk = (lane >> 4) * 8;

    f32x4 acc[4][4];
    #pragma unroll
    for (int i = 0; i < 4; ++i)
        #pragma unroll
        for (int j = 0; j < 4; ++j) acc[i][j] = (f32x4)(0.f);

    for (int k0 = 0; k0 < F_DIM; k0 += 32) {
        async_load16(aG0 + k0, aL0);
        async_load16(aG1 + k0, aL1);
        async_load16(bG0 + k0, bL0);
        async_load16(bG1 + k0, bL1);
        __syncthreads();

        bf16x8 a[4], b[4];
        #pragma unroll
        for (int i = 0; i < 4; ++i)
            a[i] = *(const bf16x8*)&As[(mbase + i * 16 + fr) * 32 + fk];
        #pragma unroll
        for (int j = 0; j < 4; ++j)
            b[j] = *(const bf16x8*)&Bs[(nbase + j * 16 + fr) * 32 + fk];
        #pragma unroll
        for (int i = 0; i < 4; ++i)
            #pragma unroll
            for (int j = 0; j < 4; ++j)
                acc[i][j] = __builtin_amdgcn_mfma_f32_16x16x32_bf16(a[i], b[j], acc[i][j], 0, 0, 0);
        __syncthreads();
    }

    const int erow = (lane >> 4) * 4;
    #pragma unroll
    for (int i = 0; i < 4; ++i) {
        #pragma unroll
        for (int r = 0; r < 4; ++r) {
            int row = mbase + i * 16 + erow + r;
            int idx = rowBase + row;
            if (idx < rows) {
                int tok2 = toks[row];
                unsigned short* orow = Hd + (size_t)tok2 * D_DIM + n0 + nbase;
                #pragma unroll
                for (int j = 0; j < 4; ++j)
                    orow[j * 16 + fr] = f2bf(acc[i][j][r]);
            }
        }
    }
}

// ---------------- Kernel 6: combine out[t] = w0*Hd[2t] + w1*Hd[2t+1] ------
__global__ __launch_bounds__(256) void combine_kernel(
    const unsigned short* __restrict__ Hd,
    const float* __restrict__ wt2,
    float* __restrict__ out)
{
    const int t = blockIdx.x;
    const int tid = threadIdx.x;
    const float w0 = wt2[2 * t];
    const float w1 = wt2[2 * t + 1];
    const int c = tid * 4;
    ushort4 a = *(const ushort4*)&Hd[(size_t)(2 * t) * D_DIM + c];
    ushort4 b = *(const ushort4*)&Hd[(size_t)(2 * t + 1) * D_DIM + c];
    float4 o;
    o.x = w0 * bf2f(a.x) + w1 * bf2f(b.x);
    o.y = w0 * bf2f(a.y) + w1 * bf2f(b.y);
    o.z = w0 * bf2f(a.z) + w1 * bf2f(b.z);
    o.w = w0 * bf2f(a.w) + w1 * bf2f(b.w);
    *(float4*)(out + (size_t)t * D_DIM + c) = o;
}

extern "C" void kernel_launch(void* const* d_in, const int* in_sizes, int n_in,
                              void* d_out, int out_size, void* d_ws, size_t ws_size,
                              hipStream_t stream) {
    const float* x  = (const float*)d_in[0];   // [B,T,D]
    const float* Wr = (const float*)d_in[1];   // [D,E]
    const float* Wg = (const float*)d_in[2];   // [E,D,F]
    const float* Wu = (const float*)d_in[3];   // [E,D,F]
    const float* Wd = (const float*)d_in[4];   // [E,F,D]
    float* out = (float*)d_out;

    char* ws = (char*)d_ws;
    int*   cnt    = (int*)ws;                               // 256 B
    int*   tok_of = (int*)(ws + 256);                       // 256 KB
    float* wt2    = (float*)(ws + 256 + E_DIM * NTOK * 4);  // 64 KB
    char*  base   = ws + (1 << 20);
    unsigned short* xb  = (unsigned short*)(base);                    // 16 MB
    unsigned short* Hd  = (unsigned short*)(base);                    // 32 MB, aliases xb+WgT (dead by then)
    unsigned short* WgT = (unsigned short*)(base + (16ll << 20));     // 16 MB
    unsigned short* WuT = (unsigned short*)(base + (32ll << 20));     // 16 MB
    unsigned short* WdT = (unsigned short*)(base + (48ll << 20));     // 16 MB
    unsigned short* H   = (unsigned short*)(base + (64ll << 20));     // 32 MB
    // total ws use: 97 MB

    hipMemsetAsync(cnt, 0, E_DIM * sizeof(int), stream);

    router_kernel<<<NTOK, 256, 0, stream>>>(x, Wr, cnt, tok_of, wt2);
    cast_x_kernel<<<NTOK * D_DIM / 1024, 256, 0, stream>>>(x, xb);
    transpose_cast_kernel<<<dim3(16, 16, 24), 256, 0, stream>>>(Wg, Wu, Wd, WgT, WuT, WdT);

    gateup_mfma<<<dim3((NTOK / 128) * (F_DIM / 128), E_DIM), 256, 0, stream>>>(
        xb, WgT, WuT, cnt, tok_of, H);
    down_mfma<<<dim3((NTOK / 128) * (D_DIM / 128), E_DIM), 256, 0, stream>>>(
        H, WdT, cnt, tok_of, Hd);
    combine_kernel<<<NTOK, 256, 0, stream>>>(Hd, wt2, out);
}

// Round 3
// 532.894 us; speedup vs baseline: 3.1287x; 1.0166x over previous
//
#include <hip/hip_runtime.h>
#include <hip/hip_bf16.h>
#include <math.h>

// B=4, T=2048, D=1024, E=8, F=1024, top_k=2
#define NTOK 8192   // B*T
#define D_DIM 1024
#define E_DIM 8
#define F_DIM 1024

typedef __attribute__((ext_vector_type(8))) short bf16x8;
typedef __attribute__((ext_vector_type(4))) float f32x4;

typedef const __attribute__((address_space(1))) unsigned int* as1_uint_ptr;
typedef __attribute__((address_space(3))) unsigned int* as3_uint_ptr;

__device__ __forceinline__ void async_load16(const void* g, void* l) {
    // per-lane global address; LDS dest = wave-uniform base + lane*16
    __builtin_amdgcn_global_load_lds((as1_uint_ptr)g, (as3_uint_ptr)l, 16, 0, 0);
}

__device__ __forceinline__ float bf2f(unsigned short b) {
    unsigned int u = ((unsigned int)b) << 16;
    return __builtin_bit_cast(float, u);
}
__device__ __forceinline__ unsigned short f2bf(float f) {
    __hip_bfloat16 h = __float2bfloat16(f);
    return __builtin_bit_cast(unsigned short, h);
}

// ---------------- Kernel 1: router (wave-per-token) + fused x->bf16 cast ----
// 4 waves/block, one token per wave. No LDS, no __syncthreads.
__global__ __launch_bounds__(256) void router_cast_kernel(
    const float* __restrict__ x,      // [NTOK][D]
    const float* __restrict__ Wr,     // [D][E]
    int* __restrict__ cnt,            // [E]
    int* __restrict__ tok_of,         // [E][NTOK] (tok2 = t*2+slot)
    float* __restrict__ wt2,          // [2*NTOK] weight by tok2
    unsigned short* __restrict__ xb)  // [NTOK][D] bf16
{
    const int wv = threadIdx.x >> 6;
    const int lane = threadIdx.x & 63;
    const int t = blockIdx.x * 4 + wv;
    const float* xrow = x + (size_t)t * D_DIM;
    unsigned short* xbrow = xb + (size_t)t * D_DIM;

    float p[E_DIM];
    #pragma unroll
    for (int e = 0; e < E_DIM; ++e) p[e] = 0.f;

    #pragma unroll
    for (int i = 0; i < 4; ++i) {
        const int d = i * 256 + lane * 4;
        float4 v = *(const float4*)(xrow + d);
        // fused bf16 cast+store (coalesced: 64 lanes x 8B contiguous)
        ushort4 o;
        o.x = f2bf(v.x); o.y = f2bf(v.y); o.z = f2bf(v.z); o.w = f2bf(v.w);
        *(ushort4*)(xbrow + d) = o;
        // accumulate logits over the 4 d values
        const float* wr = Wr + (size_t)d * E_DIM;
        float xv[4] = {v.x, v.y, v.z, v.w};
        #pragma unroll
        for (int q = 0; q < 4; ++q) {
            float4 w0 = *(const float4*)(wr + q * 8);
            float4 w1 = *(const float4*)(wr + q * 8 + 4);
            p[0] += xv[q] * w0.x; p[1] += xv[q] * w0.y;
            p[2] += xv[q] * w0.z; p[3] += xv[q] * w0.w;
            p[4] += xv[q] * w1.x; p[5] += xv[q] * w1.y;
            p[6] += xv[q] * w1.z; p[7] += xv[q] * w1.w;
        }
    }

    // butterfly reduce across the 64-lane wave
    #pragma unroll
    for (int off = 32; off > 0; off >>= 1) {
        #pragma unroll
        for (int e = 0; e < E_DIM; ++e)
            p[e] += __shfl_xor(p[e], off, 64);
    }

    if (lane == 0) {
        float m = p[0];
        #pragma unroll
        for (int e = 1; e < E_DIM; ++e) m = fmaxf(m, p[e]);
        float pr[E_DIM], sum = 0.f;
        #pragma unroll
        for (int e = 0; e < E_DIM; ++e) { pr[e] = expf(p[e] - m); sum += pr[e]; }
        float inv = 1.f / sum;
        #pragma unroll
        for (int e = 0; e < E_DIM; ++e) pr[e] *= inv;
        // top-2 (strict > keeps lowest index on ties, matching lax.top_k)
        int e0 = 0;
        #pragma unroll
        for (int e = 1; e < E_DIM; ++e) if (pr[e] > pr[e0]) e0 = e;
        int e1 = (e0 == 0) ? 1 : 0;
        #pragma unroll
        for (int e = 0; e < E_DIM; ++e) { if (e != e0 && pr[e] > pr[e1]) e1 = e; }
        // second softmax over the two PROBABILITIES (faithful to reference)
        float b = expf(pr[e1] - pr[e0]);
        float w0 = 1.f / (1.f + b);
        float w1 = b / (1.f + b);
        int pos0 = atomicAdd(&cnt[e0], 1);
        tok_of[e0 * NTOK + pos0] = t * 2 + 0;
        int pos1 = atomicAdd(&cnt[e1], 1);
        tok_of[e1 * NTOK + pos1] = t * 2 + 1;
        wt2[t * 2 + 0] = w0;
        wt2[t * 2 + 1] = w1;
    }
}

// ---------------- Kernel 3: cast+transpose weights -> [E][N][K] bf16 ------
// handles 24 matrices of 1024x1024: z<8 -> Wg, z<16 -> Wu, else Wd
__global__ __launch_bounds__(256) void transpose_cast_kernel(
    const float* __restrict__ Wg, const float* __restrict__ Wu,
    const float* __restrict__ Wd,
    unsigned short* __restrict__ WgT, unsigned short* __restrict__ WuT,
    unsigned short* __restrict__ WdT)
{
    const int m = blockIdx.z;
    const float* src;
    unsigned short* dst;
    if (m < 8)       { src = Wg + (size_t)m * 1048576;        dst = WgT + (size_t)m * 1048576; }
    else if (m < 16) { src = Wu + (size_t)(m - 8) * 1048576;  dst = WuT + (size_t)(m - 8) * 1048576; }
    else             { src = Wd + (size_t)(m - 16) * 1048576; dst = WdT + (size_t)(m - 16) * 1048576; }

    const int c0 = blockIdx.x * 64;   // src col tile (= dst row)
    const int r0 = blockIdx.y * 64;   // src row tile (= dst col)
    __shared__ float tile[64][65];
    const int tid = threadIdx.x;
    const int tr = tid >> 4;          // 0..15
    const int tc = (tid & 15) * 4;
    #pragma unroll
    for (int p = 0; p < 4; ++p) {
        float4 v = *(const float4*)(src + (size_t)(r0 + p * 16 + tr) * 1024 + c0 + tc);
        tile[p * 16 + tr][tc + 0] = v.x;
        tile[p * 16 + tr][tc + 1] = v.y;
        tile[p * 16 + tr][tc + 2] = v.z;
        tile[p * 16 + tr][tc + 3] = v.w;
    }
    __syncthreads();
    const int orow = tid >> 3;        // 0..31
    const int ocol = (tid & 7) * 8;
    #pragma unroll
    for (int p = 0; p < 2; ++p) {
        int fr = p * 32 + orow;       // dst row within tile (= src col)
        union { unsigned short s[8]; uint4 v; } pk;
        #pragma unroll
        for (int q = 0; q < 8; ++q) pk.s[q] = f2bf(tile[ocol + q][fr]);
        *(uint4*)&dst[(size_t)(c0 + fr) * 1024 + r0 + ocol] = pk.v;
    }
}

// ---------------- Kernel 4: fused gating+up MFMA GEMM + silu*mul ----------
// C = gather(x) * Wg^T / Wu^T per expert; 128x128 tile, BK=32, 4 waves.
__global__ __launch_bounds__(256, 2) void gateup_mfma(
    const unsigned short* __restrict__ xb,    // [NTOK][D] bf16
    const unsigned short* __restrict__ WgT,   // [E][F][D] bf16 (B^T)
    const unsigned short* __restrict__ WuT,   // [E][F][D] bf16
    const int* __restrict__ cnt,
    const int* __restrict__ tok_of,
    unsigned short* __restrict__ H)           // [2*NTOK][F] bf16
{
    const int e = blockIdx.y;
    const int rowTile = blockIdx.x >> 3;
    const int colTile = blockIdx.x & 7;
    const int rows = cnt[e];
    const int rowBase = rowTile * 128;
    if (rowBase >= rows) return;
    const int n0 = colTile * 128;

    __shared__ short As[128 * 32];
    __shared__ short Bg[128 * 32];
    __shared__ short Bu[128 * 32];
    __shared__ int toks[128];

    const int tid = threadIdx.x;
    if (tid < 128) {
        int idx = rowBase + tid;
        toks[tid] = tok_of[e * NTOK + (idx < rows ? idx : rows - 1)];
    }
    __syncthreads();

    const int lane = tid & 63;
    const int w = tid >> 6;
    const int seg0 = w * 2, seg1 = w * 2 + 1;   // each wave stages 2 segs per buffer
    const int sr = lane >> 2;                   // 0..15 row within segment
    const int sk = (lane & 3) * 8;              // k element offset (8 bf16 = 16B)

    const int ar0 = seg0 * 16 + sr;
    const int ar1 = seg1 * 16 + sr;
    const unsigned short* aG0 = xb + (size_t)(toks[ar0] >> 1) * D_DIM + sk;
    const unsigned short* aG1 = xb + (size_t)(toks[ar1] >> 1) * D_DIM + sk;
    const unsigned short* WgTe = WgT + (size_t)e * F_DIM * D_DIM;
    const unsigned short* WuTe = WuT + (size_t)e * F_DIM * D_DIM;
    const unsigned short* gG0 = WgTe + (size_t)(n0 + ar0) * D_DIM + sk;
    const unsigned short* gG1 = WgTe + (size_t)(n0 + ar1) * D_DIM + sk;
    const unsigned short* uG0 = WuTe + (size_t)(n0 + ar0) * D_DIM + sk;
    const unsigned short* uG1 = WuTe + (size_t)(n0 + ar1) * D_DIM + sk;

    short* aL0 = &As[seg0 * 512];   // 1 KB per segment
    short* aL1 = &As[seg1 * 512];
    short* gL0 = &Bg[seg0 * 512];
    short* gL1 = &Bg[seg1 * 512];
    short* uL0 = &Bu[seg0 * 512];
    short* uL1 = &Bu[seg1 * 512];

    const int mbase = (w >> 1) * 64;
    const int nbase = (w & 1) * 64;
    const int fr = lane & 15;
    const int fk = (lane >> 4) * 8;

    f32x4 accg[4][4], accu[4][4];
    #pragma unroll
    for (int i = 0; i < 4; ++i)
        #pragma unroll
        for (int j = 0; j < 4; ++j) { accg[i][j] = (f32x4)(0.f); accu[i][j] = (f32x4)(0.f); }

    for (int k0 = 0; k0 < D_DIM; k0 += 32) {
        async_load16(aG0 + k0, aL0);
        async_load16(aG1 + k0, aL1);
        async_load16(gG0 + k0, gL0);
        async_load16(gG1 + k0, gL1);
        async_load16(uG0 + k0, uL0);
        async_load16(uG1 + k0, uL1);
        __syncthreads();

        bf16x8 a[4], g[4], u[4];
        #pragma unroll
        for (int i = 0; i < 4; ++i)
            a[i] = *(const bf16x8*)&As[(mbase + i * 16 + fr) * 32 + fk];
        #pragma unroll
        for (int j = 0; j < 4; ++j) {
            g[j] = *(const bf16x8*)&Bg[(nbase + j * 16 + fr) * 32 + fk];
            u[j] = *(const bf16x8*)&Bu[(nbase + j * 16 + fr) * 32 + fk];
        }
        #pragma unroll
        for (int i = 0; i < 4; ++i)
            #pragma unroll
            for (int j = 0; j < 4; ++j) {
                accg[i][j] = __builtin_amdgcn_mfma_f32_16x16x32_bf16(a[i], g[j], accg[i][j], 0, 0, 0);
                accu[i][j] = __builtin_amdgcn_mfma_f32_16x16x32_bf16(a[i], u[j], accu[i][j], 0, 0, 0);
            }
        __syncthreads();
    }

    // epilogue: C/D layout col=lane&15, row=(lane>>4)*4+reg
    const int erow = (lane >> 4) * 4;
    #pragma unroll
    for (int i = 0; i < 4; ++i) {
        #pragma unroll
        for (int r = 0; r < 4; ++r) {
            int row = mbase + i * 16 + erow + r;
            int idx = rowBase + row;
            if (idx < rows) {
                int tok2 = toks[row];
                unsigned short* hrow = H + (size_t)tok2 * F_DIM + n0 + nbase;
                #pragma unroll
                for (int j = 0; j < 4; ++j) {
                    float gg = accg[i][j][r];
                    float uu = accu[i][j][r];
                    float h = gg / (1.f + __expf(-gg)) * uu;
                    hrow[j * 16 + fr] = f2bf(h);
                }
            }
        }
    }
}

// ---------------- Kernel 5: down MFMA GEMM -> Hd (unweighted) -------------
__global__ __launch_bounds__(256, 2) void down_mfma(
    const unsigned short* __restrict__ H,     // [2*NTOK][F] bf16
    const unsigned short* __restrict__ WdT,   // [E][D][F] bf16 (B^T)
    const int* __restrict__ cnt,
    const int* __restrict__ tok_of,
    unsigned short* __restrict__ Hd)          // [2*NTOK][D] bf16
{
    const int e = blockIdx.y;
    const int rowTile = blockIdx.x >> 3;
    const int colTile = blockIdx.x & 7;
    const int rows = cnt[e];
    const int rowBase = rowTile * 128;
    if (rowBase >= rows) return;
    const int n0 = colTile * 128;

    __shared__ short As[128 * 32];
    __shared__ short Bs[128 * 32];
    __shared__ int toks[128];

    const int tid = threadIdx.x;
    if (tid < 128) {
        int idx = rowBase + tid;
        toks[tid] = tok_of[e * NTOK + (idx < rows ? idx : rows - 1)];
    }
    __syncthreads();

    const int lane = tid & 63;
    const int w = tid >> 6;
    const int seg0 = w * 2, seg1 = w * 2 + 1;
    const int sr = lane >> 2;
    const int sk = (lane & 3) * 8;

    const int ar0 = seg0 * 16 + sr;
    const int ar1 = seg1 * 16 + sr;
    const unsigned short* aG0 = H + (size_t)toks[ar0] * F_DIM + sk;
    const unsigned short* aG1 = H + (size_t)toks[ar1] * F_DIM + sk;
    const unsigned short* WdTe = WdT + (size_t)e * D_DIM * F_DIM;
    const unsigned short* bG0 = WdTe + (size_t)(n0 + ar0) * F_DIM + sk;
    const unsigned short* bG1 = WdTe + (size_t)(n0 + ar1) * F_DIM + sk;

    short* aL0 = &As[seg0 * 512];
    short* aL1 = &As[seg1 * 512];
    short* bL0 = &Bs[seg0 * 512];
    short* bL1 = &Bs[seg1 * 512];

    const int mbase = (w >> 1) * 64;
    const int nbase = (w & 1) * 64;
    const int fr = lane & 15;
    const int fk = (lane >> 4) * 8;

    f32x4 acc[4][4];
    #pragma unroll
    for (int i = 0; i < 4; ++i)
        #pragma unroll
        for (int j = 0; j < 4; ++j) acc[i][j] = (f32x4)(0.f);

    for (int k0 = 0; k0 < F_DIM; k0 += 32) {
        async_load16(aG0 + k0, aL0);
        async_load16(aG1 + k0, aL1);
        async_load16(bG0 + k0, bL0);
        async_load16(bG1 + k0, bL1);
        __syncthreads();

        bf16x8 a[4], b[4];
        #pragma unroll
        for (int i = 0; i < 4; ++i)
            a[i] = *(const bf16x8*)&As[(mbase + i * 16 + fr) * 32 + fk];
        #pragma unroll
        for (int j = 0; j < 4; ++j)
            b[j] = *(const bf16x8*)&Bs[(nbase + j * 16 + fr) * 32 + fk];
        #pragma unroll
        for (int i = 0; i < 4; ++i)
            #pragma unroll
            for (int j = 0; j < 4; ++j)
                acc[i][j] = __builtin_amdgcn_mfma_f32_16x16x32_bf16(a[i], b[j], acc[i][j], 0, 0, 0);
        __syncthreads();
    }

    const int erow = (lane >> 4) * 4;
    #pragma unroll
    for (int i = 0; i < 4; ++i) {
        #pragma unroll
        for (int r = 0; r < 4; ++r) {
            int row = mbase + i * 16 + erow + r;
            int idx = rowBase + row;
            if (idx < rows) {
                int tok2 = toks[row];
                unsigned short* orow = Hd + (size_t)tok2 * D_DIM + n0 + nbase;
                #pragma unroll
                for (int j = 0; j < 4; ++j)
                    orow[j * 16 + fr] = f2bf(acc[i][j][r]);
            }
        }
    }
}

// ---------------- Kernel 6: combine out[t] = w0*Hd[2t] + w1*Hd[2t+1] ------
__global__ __launch_bounds__(256) void combine_kernel(
    const unsigned short* __restrict__ Hd,
    const float* __restrict__ wt2,
    float* __restrict__ out)
{
    const int t = blockIdx.x;
    const int tid = threadIdx.x;
    const float w0 = wt2[2 * t];
    const float w1 = wt2[2 * t + 1];
    const int c = tid * 4;
    ushort4 a = *(const ushort4*)&Hd[(size_t)(2 * t) * D_DIM + c];
    ushort4 b = *(const ushort4*)&Hd[(size_t)(2 * t + 1) * D_DIM + c];
    float4 o;
    o.x = w0 * bf2f(a.x) + w1 * bf2f(b.x);
    o.y = w0 * bf2f(a.y) + w1 * bf2f(b.y);
    o.z = w0 * bf2f(a.z) + w1 * bf2f(b.z);
    o.w = w0 * bf2f(a.w) + w1 * bf2f(b.w);
    *(float4*)(out + (size_t)t * D_DIM + c) = o;
}

extern "C" void kernel_launch(void* const* d_in, const int* in_sizes, int n_in,
                              void* d_out, int out_size, void* d_ws, size_t ws_size,
                              hipStream_t stream) {
    const float* x  = (const float*)d_in[0];   // [B,T,D]
    const float* Wr = (const float*)d_in[1];   // [D,E]
    const float* Wg = (const float*)d_in[2];   // [E,D,F]
    const float* Wu = (const float*)d_in[3];   // [E,D,F]
    const float* Wd = (const float*)d_in[4];   // [E,F,D]
    float* out = (float*)d_out;

    char* ws = (char*)d_ws;
    int*   cnt    = (int*)ws;                               // 256 B
    int*   tok_of = (int*)(ws + 256);                       // 256 KB
    float* wt2    = (float*)(ws + 256 + E_DIM * NTOK * 4);  // 64 KB
    char*  base   = ws + (1 << 20);
    unsigned short* xb  = (unsigned short*)(base);                    // 16 MB
    unsigned short* Hd  = (unsigned short*)(base);                    // 32 MB, aliases xb+WgT (dead by then)
    unsigned short* WgT = (unsigned short*)(base + (16ll << 20));     // 16 MB
    unsigned short* WuT = (unsigned short*)(base + (32ll << 20));     // 16 MB
    unsigned short* WdT = (unsigned short*)(base + (48ll << 20));     // 16 MB
    unsigned short* H   = (unsigned short*)(base + (64ll << 20));     // 32 MB
    // total ws use: 97 MB

    hipMemsetAsync(cnt, 0, E_DIM * sizeof(int), stream);

    router_cast_kernel<<<NTOK / 4, 256, 0, stream>>>(x, Wr, cnt, tok_of, wt2, xb);
    transpose_cast_kernel<<<dim3(16, 16, 24), 256, 0, stream>>>(Wg, Wu, Wd, WgT, WuT, WdT);

    gateup_mfma<<<dim3((NTOK / 128) * (F_DIM / 128), E_DIM), 256, 0, stream>>>(
        xb, WgT, WuT, cnt, tok_of, H);
    down_mfma<<<dim3((NTOK / 128) * (D_DIM / 128), E_DIM), 256, 0, stream>>>(
        H, WdT, cnt, tok_of, Hd);
    combine_kernel<<<NTOK, 256, 0, stream>>>(Hd, wt2, out);
}

// Round 4
// 377.715 us; speedup vs baseline: 4.4141x; 1.4108x over previous
//
#include <hip/hip_runtime.h>
#include <hip/hip_bf16.h>
#include <math.h>

// B=4, T=2048, D=1024, E=8, F=1024, top_k=2
#define NTOK 8192   // B*T
#define D_DIM 1024
#define E_DIM 8
#define F_DIM 1024

// cnt is padded: counter for expert e lives at cnt[e*32] (128 B apart) so the
// 8 experts' global atomics land in different L2 lines (round 3: packed
// counters serialized 16384 atomics at ~12 ns each = 200 us).
#define CNT_STRIDE 32

typedef __attribute__((ext_vector_type(8))) short bf16x8;
typedef __attribute__((ext_vector_type(4))) float f32x4;

typedef const __attribute__((address_space(1))) unsigned int* as1_uint_ptr;
typedef __attribute__((address_space(3))) unsigned int* as3_uint_ptr;

__device__ __forceinline__ void async_load16(const void* g, void* l) {
    // per-lane global address; LDS dest = wave-uniform base + lane*16
    __builtin_amdgcn_global_load_lds((as1_uint_ptr)g, (as3_uint_ptr)l, 16, 0, 0);
}

__device__ __forceinline__ float bf2f(unsigned short b) {
    unsigned int u = ((unsigned int)b) << 16;
    return __builtin_bit_cast(float, u);
}
__device__ __forceinline__ unsigned short f2bf(float f) {
    __hip_bfloat16 h = __float2bfloat16(f);
    return __builtin_bit_cast(unsigned short, h);
}

// ---------------- Kernel 1: router (wave-per-token) + fused x->bf16 cast ----
// 8 waves/block, 4 tokens per wave. Expert lists staged in LDS; one global
// atomic per (block, expert) to reserve a range in tok_of.
__global__ __launch_bounds__(512) void router_cast_kernel(
    const float* __restrict__ x,      // [NTOK][D]
    const float* __restrict__ Wr,     // [D][E]
    int* __restrict__ cnt,            // [E*CNT_STRIDE] padded counters
    int* __restrict__ tok_of,         // [E][NTOK] (tok2 = t*2+slot)
    float* __restrict__ wt2,          // [2*NTOK] weight by tok2
    unsigned short* __restrict__ xb)  // [NTOK][D] bf16
{
    __shared__ int lcnt[E_DIM];
    __shared__ int lbase[E_DIM];
    __shared__ int lbuf[E_DIM][64];   // 32 tokens * 2 slots max per expert

    const int tid = threadIdx.x;
    const int wv = tid >> 6;          // 0..7
    const int lane = tid & 63;
    if (tid < E_DIM) lcnt[tid] = 0;
    __syncthreads();

    #pragma unroll
    for (int it = 0; it < 4; ++it) {
        const int t = blockIdx.x * 32 + wv * 4 + it;
        const float* xrow = x + (size_t)t * D_DIM;
        unsigned short* xbrow = xb + (size_t)t * D_DIM;

        float p[E_DIM];
        #pragma unroll
        for (int e = 0; e < E_DIM; ++e) p[e] = 0.f;

        #pragma unroll
        for (int i = 0; i < 4; ++i) {
            const int d = i * 256 + lane * 4;
            float4 v = *(const float4*)(xrow + d);
            ushort4 o;
            o.x = f2bf(v.x); o.y = f2bf(v.y); o.z = f2bf(v.z); o.w = f2bf(v.w);
            *(ushort4*)(xbrow + d) = o;
            const float* wr = Wr + (size_t)d * E_DIM;
            float xv[4] = {v.x, v.y, v.z, v.w};
            #pragma unroll
            for (int q = 0; q < 4; ++q) {
                float4 w0 = *(const float4*)(wr + q * 8);
                float4 w1 = *(const float4*)(wr + q * 8 + 4);
                p[0] += xv[q] * w0.x; p[1] += xv[q] * w0.y;
                p[2] += xv[q] * w0.z; p[3] += xv[q] * w0.w;
                p[4] += xv[q] * w1.x; p[5] += xv[q] * w1.y;
                p[6] += xv[q] * w1.z; p[7] += xv[q] * w1.w;
            }
        }

        #pragma unroll
        for (int off = 32; off > 0; off >>= 1) {
            #pragma unroll
            for (int e = 0; e < E_DIM; ++e)
                p[e] += __shfl_xor(p[e], off, 64);
        }

        if (lane == 0) {
            float m = p[0];
            #pragma unroll
            for (int e = 1; e < E_DIM; ++e) m = fmaxf(m, p[e]);
            float pr[E_DIM], sum = 0.f;
            #pragma unroll
            for (int e = 0; e < E_DIM; ++e) { pr[e] = expf(p[e] - m); sum += pr[e]; }
            float inv = 1.f / sum;
            #pragma unroll
            for (int e = 0; e < E_DIM; ++e) pr[e] *= inv;
            // top-2 (strict > keeps lowest index on ties, matching lax.top_k)
            int e0 = 0;
            #pragma unroll
            for (int e = 1; e < E_DIM; ++e) if (pr[e] > pr[e0]) e0 = e;
            int e1 = (e0 == 0) ? 1 : 0;
            #pragma unroll
            for (int e = 0; e < E_DIM; ++e) { if (e != e0 && pr[e] > pr[e1]) e1 = e; }
            // second softmax over the two PROBABILITIES (faithful to reference)
            float b = expf(pr[e1] - pr[e0]);
            float w0 = 1.f / (1.f + b);
            float w1 = b / (1.f + b);
            int p0 = atomicAdd(&lcnt[e0], 1);
            lbuf[e0][p0] = t * 2 + 0;
            int p1 = atomicAdd(&lcnt[e1], 1);
            lbuf[e1][p1] = t * 2 + 1;
            wt2[t * 2 + 0] = w0;
            wt2[t * 2 + 1] = w1;
        }
    }
    __syncthreads();
    if (tid < E_DIM) lbase[tid] = atomicAdd(&cnt[tid * CNT_STRIDE], lcnt[tid]);
    __syncthreads();
    #pragma unroll
    for (int e = 0; e < E_DIM; ++e) {
        int n = lcnt[e];
        if (tid < n) tok_of[e * NTOK + lbase[e] + tid] = lbuf[e][tid];
    }
}

// ---------------- Kernel 3: cast+transpose weights -> [E][N][K] bf16 ------
// handles 24 matrices of 1024x1024: z<8 -> Wg, z<16 -> Wu, else Wd
__global__ __launch_bounds__(256) void transpose_cast_kernel(
    const float* __restrict__ Wg, const float* __restrict__ Wu,
    const float* __restrict__ Wd,
    unsigned short* __restrict__ WgT, unsigned short* __restrict__ WuT,
    unsigned short* __restrict__ WdT)
{
    const int m = blockIdx.z;
    const float* src;
    unsigned short* dst;
    if (m < 8)       { src = Wg + (size_t)m * 1048576;        dst = WgT + (size_t)m * 1048576; }
    else if (m < 16) { src = Wu + (size_t)(m - 8) * 1048576;  dst = WuT + (size_t)(m - 8) * 1048576; }
    else             { src = Wd + (size_t)(m - 16) * 1048576; dst = WdT + (size_t)(m - 16) * 1048576; }

    const int c0 = blockIdx.x * 64;   // src col tile (= dst row)
    const int r0 = blockIdx.y * 64;   // src row tile (= dst col)
    __shared__ float tile[64][65];
    const int tid = threadIdx.x;
    const int tr = tid >> 4;          // 0..15
    const int tc = (tid & 15) * 4;
    #pragma unroll
    for (int p = 0; p < 4; ++p) {
        float4 v = *(const float4*)(src + (size_t)(r0 + p * 16 + tr) * 1024 + c0 + tc);
        tile[p * 16 + tr][tc + 0] = v.x;
        tile[p * 16 + tr][tc + 1] = v.y;
        tile[p * 16 + tr][tc + 2] = v.z;
        tile[p * 16 + tr][tc + 3] = v.w;
    }
    __syncthreads();
    const int orow = tid >> 3;        // 0..31
    const int ocol = (tid & 7) * 8;
    #pragma unroll
    for (int p = 0; p < 2; ++p) {
        int fr = p * 32 + orow;       // dst row within tile (= src col)
        union { unsigned short s[8]; uint4 v; } pk;
        #pragma unroll
        for (int q = 0; q < 8; ++q) pk.s[q] = f2bf(tile[ocol + q][fr]);
        *(uint4*)&dst[(size_t)(c0 + fr) * 1024 + r0 + ocol] = pk.v;
    }
}

// ---------------- Kernel 4: fused gating+up MFMA GEMM + silu*mul ----------
// C = gather(x) * Wg^T / Wu^T per expert; 128x128 tile, BK=32, 4 waves.
__global__ __launch_bounds__(256, 2) void gateup_mfma(
    const unsigned short* __restrict__ xb,    // [NTOK][D] bf16
    const unsigned short* __restrict__ WgT,   // [E][F][D] bf16 (B^T)
    const unsigned short* __restrict__ WuT,   // [E][F][D] bf16
    const int* __restrict__ cnt,
    const int* __restrict__ tok_of,
    unsigned short* __restrict__ H)           // [2*NTOK][F] bf16
{
    const int e = blockIdx.y;
    const int rowTile = blockIdx.x >> 3;
    const int colTile = blockIdx.x & 7;
    const int rows = cnt[e * CNT_STRIDE];
    const int rowBase = rowTile * 128;
    if (rowBase >= rows) return;
    const int n0 = colTile * 128;

    __shared__ short As[128 * 32];
    __shared__ short Bg[128 * 32];
    __shared__ short Bu[128 * 32];
    __shared__ int toks[128];

    const int tid = threadIdx.x;
    if (tid < 128) {
        int idx = rowBase + tid;
        toks[tid] = tok_of[e * NTOK + (idx < rows ? idx : rows - 1)];
    }
    __syncthreads();

    const int lane = tid & 63;
    const int w = tid >> 6;
    const int seg0 = w * 2, seg1 = w * 2 + 1;   // each wave stages 2 segs per buffer
    const int sr = lane >> 2;                   // 0..15 row within segment
    const int sk = (lane & 3) * 8;              // k element offset (8 bf16 = 16B)

    const int ar0 = seg0 * 16 + sr;
    const int ar1 = seg1 * 16 + sr;
    const unsigned short* aG0 = xb + (size_t)(toks[ar0] >> 1) * D_DIM + sk;
    const unsigned short* aG1 = xb + (size_t)(toks[ar1] >> 1) * D_DIM + sk;
    const unsigned short* WgTe = WgT + (size_t)e * F_DIM * D_DIM;
    const unsigned short* WuTe = WuT + (size_t)e * F_DIM * D_DIM;
    const unsigned short* gG0 = WgTe + (size_t)(n0 + ar0) * D_DIM + sk;
    const unsigned short* gG1 = WgTe + (size_t)(n0 + ar1) * D_DIM + sk;
    const unsigned short* uG0 = WuTe + (size_t)(n0 + ar0) * D_DIM + sk;
    const unsigned short* uG1 = WuTe + (size_t)(n0 + ar1) * D_DIM + sk;

    short* aL0 = &As[seg0 * 512];   // 1 KB per segment
    short* aL1 = &As[seg1 * 512];
    short* gL0 = &Bg[seg0 * 512];
    short* gL1 = &Bg[seg1 * 512];
    short* uL0 = &Bu[seg0 * 512];
    short* uL1 = &Bu[seg1 * 512];

    const int mbase = (w >> 1) * 64;
    const int nbase = (w & 1) * 64;
    const int fr = lane & 15;
    const int fk = (lane >> 4) * 8;

    f32x4 accg[4][4], accu[4][4];
    #pragma unroll
    for (int i = 0; i < 4; ++i)
        #pragma unroll
        for (int j = 0; j < 4; ++j) { accg[i][j] = (f32x4)(0.f); accu[i][j] = (f32x4)(0.f); }

    for (int k0 = 0; k0 < D_DIM; k0 += 32) {
        async_load16(aG0 + k0, aL0);
        async_load16(aG1 + k0, aL1);
        async_load16(gG0 + k0, gL0);
        async_load16(gG1 + k0, gL1);
        async_load16(uG0 + k0, uL0);
        async_load16(uG1 + k0, uL1);
        __syncthreads();

        bf16x8 a[4], g[4], u[4];
        #pragma unroll
        for (int i = 0; i < 4; ++i)
            a[i] = *(const bf16x8*)&As[(mbase + i * 16 + fr) * 32 + fk];
        #pragma unroll
        for (int j = 0; j < 4; ++j) {
            g[j] = *(const bf16x8*)&Bg[(nbase + j * 16 + fr) * 32 + fk];
            u[j] = *(const bf16x8*)&Bu[(nbase + j * 16 + fr) * 32 + fk];
        }
        #pragma unroll
        for (int i = 0; i < 4; ++i)
            #pragma unroll
            for (int j = 0; j < 4; ++j) {
                accg[i][j] = __builtin_amdgcn_mfma_f32_16x16x32_bf16(a[i], g[j], accg[i][j], 0, 0, 0);
                accu[i][j] = __builtin_amdgcn_mfma_f32_16x16x32_bf16(a[i], u[j], accu[i][j], 0, 0, 0);
            }
        __syncthreads();
    }

    // epilogue: C/D layout col=lane&15, row=(lane>>4)*4+reg
    const int erow = (lane >> 4) * 4;
    #pragma unroll
    for (int i = 0; i < 4; ++i) {
        #pragma unroll
        for (int r = 0; r < 4; ++r) {
            int row = mbase + i * 16 + erow + r;
            int idx = rowBase + row;
            if (idx < rows) {
                int tok2 = toks[row];
                unsigned short* hrow = H + (size_t)tok2 * F_DIM + n0 + nbase;
                #pragma unroll
                for (int j = 0; j < 4; ++j) {
                    float gg = accg[i][j][r];
                    float uu = accu[i][j][r];
                    float h = gg / (1.f + __expf(-gg)) * uu;
                    hrow[j * 16 + fr] = f2bf(h);
                }
            }
        }
    }
}

// ---------------- Kernel 5: down MFMA GEMM -> Hd (unweighted) -------------
__global__ __launch_bounds__(256, 2) void down_mfma(
    const unsigned short* __restrict__ H,     // [2*NTOK][F] bf16
    const unsigned short* __restrict__ WdT,   // [E][D][F] bf16 (B^T)
    const int* __restrict__ cnt,
    const int* __restrict__ tok_of,
    unsigned short* __restrict__ Hd)          // [2*NTOK][D] bf16
{
    const int e = blockIdx.y;
    const int rowTile = blockIdx.x >> 3;
    const int colTile = blockIdx.x & 7;
    const int rows = cnt[e * CNT_STRIDE];
    const int rowBase = rowTile * 128;
    if (rowBase >= rows) return;
    const int n0 = colTile * 128;

    __shared__ short As[128 * 32];
    __shared__ short Bs[128 * 32];
    __shared__ int toks[128];

    const int tid = threadIdx.x;
    if (tid < 128) {
        int idx = rowBase + tid;
        toks[tid] = tok_of[e * NTOK + (idx < rows ? idx : rows - 1)];
    }
    __syncthreads();

    const int lane = tid & 63;
    const int w = tid >> 6;
    const int seg0 = w * 2, seg1 = w * 2 + 1;
    const int sr = lane >> 2;
    const int sk = (lane & 3) * 8;

    const int ar0 = seg0 * 16 + sr;
    const int ar1 = seg1 * 16 + sr;
    const unsigned short* aG0 = H + (size_t)toks[ar0] * F_DIM + sk;
    const unsigned short* aG1 = H + (size_t)toks[ar1] * F_DIM + sk;
    const unsigned short* WdTe = WdT + (size_t)e * D_DIM * F_DIM;
    const unsigned short* bG0 = WdTe + (size_t)(n0 + ar0) * F_DIM + sk;
    const unsigned short* bG1 = WdTe + (size_t)(n0 + ar1) * F_DIM + sk;

    short* aL0 = &As[seg0 * 512];
    short* aL1 = &As[seg1 * 512];
    short* bL0 = &Bs[seg0 * 512];
    short* bL1 = &Bs[seg1 * 512];

    const int mbase = (w >> 1) * 64;
    const int nbase = (w & 1) * 64;
    const int fr = lane & 15;
    const int fk = (lane >> 4) * 8;

    f32x4 acc[4][4];
    #pragma unroll
    for (int i = 0; i < 4; ++i)
        #pragma unroll
        for (int j = 0; j < 4; ++j) acc[i][j] = (f32x4)(0.f);

    for (int k0 = 0; k0 < F_DIM; k0 += 32) {
        async_load16(aG0 + k0, aL0);
        async_load16(aG1 + k0, aL1);
        async_load16(bG0 + k0, bL0);
        async_load16(bG1 + k0, bL1);
        __syncthreads();

        bf16x8 a[4], b[4];
        #pragma unroll
        for (int i = 0; i < 4; ++i)
            a[i] = *(const bf16x8*)&As[(mbase + i * 16 + fr) * 32 + fk];
        #pragma unroll
        for (int j = 0; j < 4; ++j)
            b[j] = *(const bf16x8*)&Bs[(nbase + j * 16 + fr) * 32 + fk];
        #pragma unroll
        for (int i = 0; i < 4; ++i)
            #pragma unroll
            for (int j = 0; j < 4; ++j)
                acc[i][j] = __builtin_amdgcn_mfma_f32_16x16x32_bf16(a[i], b[j], acc[i][j], 0, 0, 0);
        __syncthreads();
    }

    const int erow = (lane >> 4) * 4;
    #pragma unroll
    for (int i = 0; i < 4; ++i) {
        #pragma unroll
        for (int r = 0; r < 4; ++r) {
            int row = mbase + i * 16 + erow + r;
            int idx = rowBase + row;
            if (idx < rows) {
                int tok2 = toks[row];
                unsigned short* orow = Hd + (size_t)tok2 * D_DIM + n0 + nbase;
                #pragma unroll
                for (int j = 0; j < 4; ++j)
                    orow[j * 16 + fr] = f2bf(acc[i][j][r]);
            }
        }
    }
}

// ---------------- Kernel 6: combine out[t] = w0*Hd[2t] + w1*Hd[2t+1] ------
__global__ __launch_bounds__(256) void combine_kernel(
    const unsigned short* __restrict__ Hd,
    const float* __restrict__ wt2,
    float* __restrict__ out)
{
    const int t = blockIdx.x;
    const int tid = threadIdx.x;
    const float w0 = wt2[2 * t];
    const float w1 = wt2[2 * t + 1];
    const int c = tid * 4;
    ushort4 a = *(const ushort4*)&Hd[(size_t)(2 * t) * D_DIM + c];
    ushort4 b = *(const ushort4*)&Hd[(size_t)(2 * t + 1) * D_DIM + c];
    float4 o;
    o.x = w0 * bf2f(a.x) + w1 * bf2f(b.x);
    o.y = w0 * bf2f(a.y) + w1 * bf2f(b.y);
    o.z = w0 * bf2f(a.z) + w1 * bf2f(b.z);
    o.w = w0 * bf2f(a.w) + w1 * bf2f(b.w);
    *(float4*)(out + (size_t)t * D_DIM + c) = o;
}

extern "C" void kernel_launch(void* const* d_in, const int* in_sizes, int n_in,
                              void* d_out, int out_size, void* d_ws, size_t ws_size,
                              hipStream_t stream) {
    const float* x  = (const float*)d_in[0];   // [B,T,D]
    const float* Wr = (const float*)d_in[1];   // [D,E]
    const float* Wg = (const float*)d_in[2];   // [E,D,F]
    const float* Wu = (const float*)d_in[3];   // [E,D,F]
    const float* Wd = (const float*)d_in[4];   // [E,F,D]
    float* out = (float*)d_out;

    char* ws = (char*)d_ws;
    int*   cnt    = (int*)ws;                                // 1 KB (padded counters)
    int*   tok_of = (int*)(ws + 1024);                       // 256 KB
    float* wt2    = (float*)(ws + 1024 + E_DIM * NTOK * 4);  // 64 KB
    char*  base   = ws + (1 << 20);
    unsigned short* xb  = (unsigned short*)(base);                    // 16 MB
    unsigned short* Hd  = (unsigned short*)(base);                    // 32 MB, aliases xb+WgT (dead by then)
    unsigned short* WgT = (unsigned short*)(base + (16ll << 20));     // 16 MB
    unsigned short* WuT = (unsigned short*)(base + (32ll << 20));     // 16 MB
    unsigned short* WdT = (unsigned short*)(base + (48ll << 20));     // 16 MB
    unsigned short* H   = (unsigned short*)(base + (64ll << 20));     // 32 MB
    // total ws use: 97 MB

    hipMemsetAsync(cnt, 0, E_DIM * CNT_STRIDE * sizeof(int), stream);

    router_cast_kernel<<<NTOK / 32, 512, 0, stream>>>(x, Wr, cnt, tok_of, wt2, xb);
    transpose_cast_kernel<<<dim3(16, 16, 24), 256, 0, stream>>>(Wg, Wu, Wd, WgT, WuT, WdT);

    gateup_mfma<<<dim3((NTOK / 128) * (F_DIM / 128), E_DIM), 256, 0, stream>>>(
        xb, WgT, WuT, cnt, tok_of, H);
    down_mfma<<<dim3((NTOK / 128) * (D_DIM / 128), E_DIM), 256, 0, stream>>>(
        H, WdT, cnt, tok_of, Hd);
    combine_kernel<<<NTOK, 256, 0, stream>>>(Hd, wt2, out);
}

// Round 5
// 372.869 us; speedup vs baseline: 4.4715x; 1.0130x over previous
//
#include <hip/hip_runtime.h>
#include <hip/hip_bf16.h>
#include <math.h>

// B=4, T=2048, D=1024, E=8, F=1024, top_k=2
#define NTOK 8192   // B*T
#define D_DIM 1024
#define E_DIM 8
#define F_DIM 1024

// cnt is padded: counter for expert e lives at cnt[e*32] (128 B apart) so the
// 8 experts' global atomics land in different L2 lines (round 3: packed
// counters serialized 16384 atomics at ~12 ns each = 200 us).
#define CNT_STRIDE 32

typedef __attribute__((ext_vector_type(8))) short bf16x8;
typedef __attribute__((ext_vector_type(4))) float f32x4;

typedef const __attribute__((address_space(1))) unsigned int* as1_uint_ptr;
typedef __attribute__((address_space(3))) unsigned int* as3_uint_ptr;

__device__ __forceinline__ void async_load16(const void* g, void* l) {
    // per-lane global address; LDS dest = wave-uniform base + lane*16
    __builtin_amdgcn_global_load_lds((as1_uint_ptr)g, (as3_uint_ptr)l, 16, 0, 0);
}

__device__ __forceinline__ float bf2f(unsigned short b) {
    unsigned int u = ((unsigned int)b) << 16;
    return __builtin_bit_cast(float, u);
}
__device__ __forceinline__ unsigned short f2bf(float f) {
    __hip_bfloat16 h = __float2bfloat16(f);
    return __builtin_bit_cast(unsigned short, h);
}

// LDS swizzle (round 5): the naive staged layout gives fragment reads a
// 64 B lane stride -> 8-way bank conflict (6.5M SQ_LDS_BANK_CONFLICT,
// 2.94x LDS cost). Stage lane s loads k-chunk (s&3)^((row>>1)&3) instead;
// readers invert it. 16-lane read groups then hit every bank-group exactly
// 2x (2-way = free per m136). Staging global coalescing is unchanged
// (each quarter-wave still reads whole 64 B row-chunks).

// ---------------- Kernel 1: router (wave-per-token) + fused x->bf16 cast ----
// 8 waves/block, 4 tokens per wave. Expert lists staged in LDS; one global
// atomic per (block, expert) to reserve a range in tok_of.
__global__ __launch_bounds__(512) void router_cast_kernel(
    const float* __restrict__ x,      // [NTOK][D]
    const float* __restrict__ Wr,     // [D][E]
    int* __restrict__ cnt,            // [E*CNT_STRIDE] padded counters
    int* __restrict__ tok_of,         // [E][NTOK] (tok2 = t*2+slot)
    float* __restrict__ wt2,          // [2*NTOK] weight by tok2
    unsigned short* __restrict__ xb)  // [NTOK][D] bf16
{
    __shared__ int lcnt[E_DIM];
    __shared__ int lbase[E_DIM];
    __shared__ int lbuf[E_DIM][64];   // 32 tokens * 2 slots max per expert

    const int tid = threadIdx.x;
    const int wv = tid >> 6;          // 0..7
    const int lane = tid & 63;
    if (tid < E_DIM) lcnt[tid] = 0;
    __syncthreads();

    #pragma unroll
    for (int it = 0; it < 4; ++it) {
        const int t = blockIdx.x * 32 + wv * 4 + it;
        const float* xrow = x + (size_t)t * D_DIM;
        unsigned short* xbrow = xb + (size_t)t * D_DIM;

        float p[E_DIM];
        #pragma unroll
        for (int e = 0; e < E_DIM; ++e) p[e] = 0.f;

        #pragma unroll
        for (int i = 0; i < 4; ++i) {
            const int d = i * 256 + lane * 4;
            float4 v = *(const float4*)(xrow + d);
            ushort4 o;
            o.x = f2bf(v.x); o.y = f2bf(v.y); o.z = f2bf(v.z); o.w = f2bf(v.w);
            *(ushort4*)(xbrow + d) = o;
            const float* wr = Wr + (size_t)d * E_DIM;
            float xv[4] = {v.x, v.y, v.z, v.w};
            #pragma unroll
            for (int q = 0; q < 4; ++q) {
                float4 w0 = *(const float4*)(wr + q * 8);
                float4 w1 = *(const float4*)(wr + q * 8 + 4);
                p[0] += xv[q] * w0.x; p[1] += xv[q] * w0.y;
                p[2] += xv[q] * w0.z; p[3] += xv[q] * w0.w;
                p[4] += xv[q] * w1.x; p[5] += xv[q] * w1.y;
                p[6] += xv[q] * w1.z; p[7] += xv[q] * w1.w;
            }
        }

        #pragma unroll
        for (int off = 32; off > 0; off >>= 1) {
            #pragma unroll
            for (int e = 0; e < E_DIM; ++e)
                p[e] += __shfl_xor(p[e], off, 64);
        }

        if (lane == 0) {
            float m = p[0];
            #pragma unroll
            for (int e = 1; e < E_DIM; ++e) m = fmaxf(m, p[e]);
            float pr[E_DIM], sum = 0.f;
            #pragma unroll
            for (int e = 0; e < E_DIM; ++e) { pr[e] = expf(p[e] - m); sum += pr[e]; }
            float inv = 1.f / sum;
            #pragma unroll
            for (int e = 0; e < E_DIM; ++e) pr[e] *= inv;
            // top-2 (strict > keeps lowest index on ties, matching lax.top_k)
            int e0 = 0;
            #pragma unroll
            for (int e = 1; e < E_DIM; ++e) if (pr[e] > pr[e0]) e0 = e;
            int e1 = (e0 == 0) ? 1 : 0;
            #pragma unroll
            for (int e = 0; e < E_DIM; ++e) { if (e != e0 && pr[e] > pr[e1]) e1 = e; }
            // second softmax over the two PROBABILITIES (faithful to reference)
            float b = expf(pr[e1] - pr[e0]);
            float w0 = 1.f / (1.f + b);
            float w1 = b / (1.f + b);
            int p0 = atomicAdd(&lcnt[e0], 1);
            lbuf[e0][p0] = t * 2 + 0;
            int p1 = atomicAdd(&lcnt[e1], 1);
            lbuf[e1][p1] = t * 2 + 1;
            wt2[t * 2 + 0] = w0;
            wt2[t * 2 + 1] = w1;
        }
    }
    __syncthreads();
    if (tid < E_DIM) lbase[tid] = atomicAdd(&cnt[tid * CNT_STRIDE], lcnt[tid]);
    __syncthreads();
    #pragma unroll
    for (int e = 0; e < E_DIM; ++e) {
        int n = lcnt[e];
        if (tid < n) tok_of[e * NTOK + lbase[e] + tid] = lbuf[e][tid];
    }
}

// ---------------- Kernel 3: cast+transpose weights -> [E][N][K] bf16 ------
// handles 24 matrices of 1024x1024: z<8 -> Wg, z<16 -> Wu, else Wd
__global__ __launch_bounds__(256) void transpose_cast_kernel(
    const float* __restrict__ Wg, const float* __restrict__ Wu,
    const float* __restrict__ Wd,
    unsigned short* __restrict__ WgT, unsigned short* __restrict__ WuT,
    unsigned short* __restrict__ WdT)
{
    const int m = blockIdx.z;
    const float* src;
    unsigned short* dst;
    if (m < 8)       { src = Wg + (size_t)m * 1048576;        dst = WgT + (size_t)m * 1048576; }
    else if (m < 16) { src = Wu + (size_t)(m - 8) * 1048576;  dst = WuT + (size_t)(m - 8) * 1048576; }
    else             { src = Wd + (size_t)(m - 16) * 1048576; dst = WdT + (size_t)(m - 16) * 1048576; }

    const int c0 = blockIdx.x * 64;   // src col tile (= dst row)
    const int r0 = blockIdx.y * 64;   // src row tile (= dst col)
    __shared__ float tile[64][65];
    const int tid = threadIdx.x;
    const int tr = tid >> 4;          // 0..15
    const int tc = (tid & 15) * 4;
    #pragma unroll
    for (int p = 0; p < 4; ++p) {
        float4 v = *(const float4*)(src + (size_t)(r0 + p * 16 + tr) * 1024 + c0 + tc);
        tile[p * 16 + tr][tc + 0] = v.x;
        tile[p * 16 + tr][tc + 1] = v.y;
        tile[p * 16 + tr][tc + 2] = v.z;
        tile[p * 16 + tr][tc + 3] = v.w;
    }
    __syncthreads();
    const int orow = tid >> 3;        // 0..31
    const int ocol = (tid & 7) * 8;
    #pragma unroll
    for (int p = 0; p < 2; ++p) {
        int fr = p * 32 + orow;       // dst row within tile (= src col)
        union { unsigned short s[8]; uint4 v; } pk;
        #pragma unroll
        for (int q = 0; q < 8; ++q) pk.s[q] = f2bf(tile[ocol + q][fr]);
        *(uint4*)&dst[(size_t)(c0 + fr) * 1024 + r0 + ocol] = pk.v;
    }
}

// ---------------- Kernel 4: fused gating+up MFMA GEMM + silu*mul ----------
// C = gather(x) * Wg^T / Wu^T per expert; 128x128 tile, BK=32, 4 waves.
__global__ __launch_bounds__(256, 2) void gateup_mfma(
    const unsigned short* __restrict__ xb,    // [NTOK][D] bf16
    const unsigned short* __restrict__ WgT,   // [E][F][D] bf16 (B^T)
    const unsigned short* __restrict__ WuT,   // [E][F][D] bf16
    const int* __restrict__ cnt,
    const int* __restrict__ tok_of,
    unsigned short* __restrict__ H)           // [2*NTOK][F] bf16
{
    const int e = blockIdx.y;
    const int rowTile = blockIdx.x >> 3;
    const int colTile = blockIdx.x & 7;
    const int rows = cnt[e * CNT_STRIDE];
    const int rowBase = rowTile * 128;
    if (rowBase >= rows) return;
    const int n0 = colTile * 128;

    __shared__ short As[128 * 32];
    __shared__ short Bg[128 * 32];
    __shared__ short Bu[128 * 32];
    __shared__ int toks[128];

    const int tid = threadIdx.x;
    if (tid < 128) {
        int idx = rowBase + tid;
        toks[tid] = tok_of[e * NTOK + (idx < rows ? idx : rows - 1)];
    }
    __syncthreads();

    const int lane = tid & 63;
    const int w = tid >> 6;
    const int seg0 = w * 2, seg1 = w * 2 + 1;   // each wave stages 2 segs per buffer
    const int sr = lane >> 2;                   // 0..15 row within segment
    const int swz = (sr >> 1) & 3;
    const int sk = ((lane & 3) ^ swz) * 8;      // swizzled k-chunk (8 bf16 = 16B)

    const int ar0 = seg0 * 16 + sr;
    const int ar1 = seg1 * 16 + sr;
    const unsigned short* aG0 = xb + (size_t)(toks[ar0] >> 1) * D_DIM + sk;
    const unsigned short* aG1 = xb + (size_t)(toks[ar1] >> 1) * D_DIM + sk;
    const unsigned short* WgTe = WgT + (size_t)e * F_DIM * D_DIM;
    const unsigned short* WuTe = WuT + (size_t)e * F_DIM * D_DIM;
    const unsigned short* gG0 = WgTe + (size_t)(n0 + ar0) * D_DIM + sk;
    const unsigned short* gG1 = WgTe + (size_t)(n0 + ar1) * D_DIM + sk;
    const unsigned short* uG0 = WuTe + (size_t)(n0 + ar0) * D_DIM + sk;
    const unsigned short* uG1 = WuTe + (size_t)(n0 + ar1) * D_DIM + sk;

    short* aL0 = &As[seg0 * 512];   // 1 KB per segment
    short* aL1 = &As[seg1 * 512];
    short* gL0 = &Bg[seg0 * 512];
    short* gL1 = &Bg[seg1 * 512];
    short* uL0 = &Bu[seg0 * 512];
    short* uL1 = &Bu[seg1 * 512];

    const int mseg = (w >> 1) * 4;   // A segment base for this wave
    const int nseg = (w & 1) * 4;    // B segment base
    const int mbase = (w >> 1) * 64;
    const int nbase = (w & 1) * 64;
    const int fr = lane & 15;
    // reader offset within a segment (shorts): inverse of the staging swizzle
    const int rd = (4 * fr + ((lane >> 4) ^ ((fr >> 1) & 3))) * 8;

    f32x4 accg[4][4], accu[4][4];
    #pragma unroll
    for (int i = 0; i < 4; ++i)
        #pragma unroll
        for (int j = 0; j < 4; ++j) { accg[i][j] = (f32x4)(0.f); accu[i][j] = (f32x4)(0.f); }

    for (int k0 = 0; k0 < D_DIM; k0 += 32) {
        async_load16(aG0 + k0, aL0);
        async_load16(aG1 + k0, aL1);
        async_load16(gG0 + k0, gL0);
        async_load16(gG1 + k0, gL1);
        async_load16(uG0 + k0, uL0);
        async_load16(uG1 + k0, uL1);
        __syncthreads();

        bf16x8 a[4], g[4], u[4];
        #pragma unroll
        for (int i = 0; i < 4; ++i)
            a[i] = *(const bf16x8*)&As[(mseg + i) * 512 + rd];
        #pragma unroll
        for (int j = 0; j < 4; ++j) {
            g[j] = *(const bf16x8*)&Bg[(nseg + j) * 512 + rd];
            u[j] = *(const bf16x8*)&Bu[(nseg + j) * 512 + rd];
        }
        #pragma unroll
        for (int i = 0; i < 4; ++i)
            #pragma unroll
            for (int j = 0; j < 4; ++j) {
                accg[i][j] = __builtin_amdgcn_mfma_f32_16x16x32_bf16(a[i], g[j], accg[i][j], 0, 0, 0);
                accu[i][j] = __builtin_amdgcn_mfma_f32_16x16x32_bf16(a[i], u[j], accu[i][j], 0, 0, 0);
            }
        __syncthreads();
    }

    // epilogue: C/D layout col=lane&15, row=(lane>>4)*4+reg
    const int erow = (lane >> 4) * 4;
    #pragma unroll
    for (int i = 0; i < 4; ++i) {
        #pragma unroll
        for (int r = 0; r < 4; ++r) {
            int row = mbase + i * 16 + erow + r;
            int idx = rowBase + row;
            if (idx < rows) {
                int tok2 = toks[row];
                unsigned short* hrow = H + (size_t)tok2 * F_DIM + n0 + nbase;
                #pragma unroll
                for (int j = 0; j < 4; ++j) {
                    float gg = accg[i][j][r];
                    float uu = accu[i][j][r];
                    float h = gg / (1.f + __expf(-gg)) * uu;
                    hrow[j * 16 + fr] = f2bf(h);
                }
            }
        }
    }
}

// ---------------- Kernel 5: down MFMA GEMM -> Hd (unweighted) -------------
__global__ __launch_bounds__(256, 2) void down_mfma(
    const unsigned short* __restrict__ H,     // [2*NTOK][F] bf16
    const unsigned short* __restrict__ WdT,   // [E][D][F] bf16 (B^T)
    const int* __restrict__ cnt,
    const int* __restrict__ tok_of,
    unsigned short* __restrict__ Hd)          // [2*NTOK][D] bf16
{
    const int e = blockIdx.y;
    const int rowTile = blockIdx.x >> 3;
    const int colTile = blockIdx.x & 7;
    const int rows = cnt[e * CNT_STRIDE];
    const int rowBase = rowTile * 128;
    if (rowBase >= rows) return;
    const int n0 = colTile * 128;

    __shared__ short As[128 * 32];
    __shared__ short Bs[128 * 32];
    __shared__ int toks[128];

    const int tid = threadIdx.x;
    if (tid < 128) {
        int idx = rowBase + tid;
        toks[tid] = tok_of[e * NTOK + (idx < rows ? idx : rows - 1)];
    }
    __syncthreads();

    const int lane = tid & 63;
    const int w = tid >> 6;
    const int seg0 = w * 2, seg1 = w * 2 + 1;
    const int sr = lane >> 2;
    const int swz = (sr >> 1) & 3;
    const int sk = ((lane & 3) ^ swz) * 8;

    const int ar0 = seg0 * 16 + sr;
    const int ar1 = seg1 * 16 + sr;
    const unsigned short* aG0 = H + (size_t)toks[ar0] * F_DIM + sk;
    const unsigned short* aG1 = H + (size_t)toks[ar1] * F_DIM + sk;
    const unsigned short* WdTe = WdT + (size_t)e * D_DIM * F_DIM;
    const unsigned short* bG0 = WdTe + (size_t)(n0 + ar0) * F_DIM + sk;
    const unsigned short* bG1 = WdTe + (size_t)(n0 + ar1) * F_DIM + sk;

    short* aL0 = &As[seg0 * 512];
    short* aL1 = &As[seg1 * 512];
    short* bL0 = &Bs[seg0 * 512];
    short* bL1 = &Bs[seg1 * 512];

    const int mseg = (w >> 1) * 4;
    const int nseg = (w & 1) * 4;
    const int mbase = (w >> 1) * 64;
    const int nbase = (w & 1) * 64;
    const int fr = lane & 15;
    const int rd = (4 * fr + ((lane >> 4) ^ ((fr >> 1) & 3))) * 8;

    f32x4 acc[4][4];
    #pragma unroll
    for (int i = 0; i < 4; ++i)
        #pragma unroll
        for (int j = 0; j < 4; ++j) acc[i][j] = (f32x4)(0.f);

    for (int k0 = 0; k0 < F_DIM; k0 += 32) {
        async_load16(aG0 + k0, aL0);
        async_load16(aG1 + k0, aL1);
        async_load16(bG0 + k0, bL0);
        async_load16(bG1 + k0, bL1);
        __syncthreads();

        bf16x8 a[4], b[4];
        #pragma unroll
        for (int i = 0; i < 4; ++i)
            a[i] = *(const bf16x8*)&As[(mseg + i) * 512 + rd];
        #pragma unroll
        for (int j = 0; j < 4; ++j)
            b[j] = *(const bf16x8*)&Bs[(nseg + j) * 512 + rd];
        #pragma unroll
        for (int i = 0; i < 4; ++i)
            #pragma unroll
            for (int j = 0; j < 4; ++j)
                acc[i][j] = __builtin_amdgcn_mfma_f32_16x16x32_bf16(a[i], b[j], acc[i][j], 0, 0, 0);
        __syncthreads();
    }

    const int erow = (lane >> 4) * 4;
    #pragma unroll
    for (int i = 0; i < 4; ++i) {
        #pragma unroll
        for (int r = 0; r < 4; ++r) {
            int row = mbase + i * 16 + erow + r;
            int idx = rowBase + row;
            if (idx < rows) {
                int tok2 = toks[row];
                unsigned short* orow = Hd + (size_t)tok2 * D_DIM + n0 + nbase;
                #pragma unroll
                for (int j = 0; j < 4; ++j)
                    orow[j * 16 + fr] = f2bf(acc[i][j][r]);
            }
        }
    }
}

// ---------------- Kernel 6: combine out[t] = w0*Hd[2t] + w1*Hd[2t+1] ------
__global__ __launch_bounds__(256) void combine_kernel(
    const unsigned short* __restrict__ Hd,
    const float* __restrict__ wt2,
    float* __restrict__ out)
{
    const int t = blockIdx.x;
    const int tid = threadIdx.x;
    const float w0 = wt2[2 * t];
    const float w1 = wt2[2 * t + 1];
    const int c = tid * 4;
    ushort4 a = *(const ushort4*)&Hd[(size_t)(2 * t) * D_DIM + c];
    ushort4 b = *(const ushort4*)&Hd[(size_t)(2 * t + 1) * D_DIM + c];
    float4 o;
    o.x = w0 * bf2f(a.x) + w1 * bf2f(b.x);
    o.y = w0 * bf2f(a.y) + w1 * bf2f(b.y);
    o.z = w0 * bf2f(a.z) + w1 * bf2f(b.z);
    o.w = w0 * bf2f(a.w) + w1 * bf2f(b.w);
    *(float4*)(out + (size_t)t * D_DIM + c) = o;
}

extern "C" void kernel_launch(void* const* d_in, const int* in_sizes, int n_in,
                              void* d_out, int out_size, void* d_ws, size_t ws_size,
                              hipStream_t stream) {
    const float* x  = (const float*)d_in[0];   // [B,T,D]
    const float* Wr = (const float*)d_in[1];   // [D,E]
    const float* Wg = (const float*)d_in[2];   // [E,D,F]
    const float* Wu = (const float*)d_in[3];   // [E,D,F]
    const float* Wd = (const float*)d_in[4];   // [E,F,D]
    float* out = (float*)d_out;

    char* ws = (char*)d_ws;
    int*   cnt    = (int*)ws;                                // 1 KB (padded counters)
    int*   tok_of = (int*)(ws + 1024);                       // 256 KB
    float* wt2    = (float*)(ws + 1024 + E_DIM * NTOK * 4);  // 64 KB
    char*  base   = ws + (1 << 20);
    unsigned short* xb  = (unsigned short*)(base);                    // 16 MB
    unsigned short* Hd  = (unsigned short*)(base);                    // 32 MB, aliases xb+WgT (dead by then)
    unsigned short* WgT = (unsigned short*)(base + (16ll << 20));     // 16 MB
    unsigned short* WuT = (unsigned short*)(base + (32ll << 20));     // 16 MB
    unsigned short* WdT = (unsigned short*)(base + (48ll << 20));     // 16 MB
    unsigned short* H   = (unsigned short*)(base + (64ll << 20));     // 32 MB
    // total ws use: 97 MB

    hipMemsetAsync(cnt, 0, E_DIM * CNT_STRIDE * sizeof(int), stream);

    router_cast_kernel<<<NTOK / 32, 512, 0, stream>>>(x, Wr, cnt, tok_of, wt2, xb);
    transpose_cast_kernel<<<dim3(16, 16, 24), 256, 0, stream>>>(Wg, Wu, Wd, WgT, WuT, WdT);

    gateup_mfma<<<dim3((NTOK / 128) * (F_DIM / 128), E_DIM), 256, 0, stream>>>(
        xb, WgT, WuT, cnt, tok_of, H);
    down_mfma<<<dim3((NTOK / 128) * (D_DIM / 128), E_DIM), 256, 0, stream>>>(
        H, WdT, cnt, tok_of, Hd);
    combine_kernel<<<NTOK, 256, 0, stream>>>(Hd, wt2, out);
}